// Round 7
// baseline (268.674 us; speedup 1.0000x reference)
//
#include <hip/hip_runtime.h>
#include <hip/hip_bf16.h>
#include <cstdint>

#define NN 50000
#define NE 600000
#define DD 128
#define ROWS 32
#define SCAN_BLKS 49   // ceil(50000/1024)

// ws layout: counts[NN] | offsets[NN] | cursor[NN] | srcs[NE] | blocksums[64]
//            | blockoffs[64] | xb16[NN*DD] (as uint16)   (~15.9 MB total)

__device__ __forceinline__ unsigned short f32_to_bf16_rne(float f) {
    unsigned int u = __float_as_uint(f);
    unsigned int r = (u + 0x7FFFu + ((u >> 16) & 1u)) >> 16;   // RNE
    return (unsigned short)r;
}

// ---------------------------------------------------------------------------
// Kernel 0: convert x -> bf16 (gather working set 25.6 -> 12.8 MB)
// ---------------------------------------------------------------------------
__global__ __launch_bounds__(256) void xcvt_kernel(
    const float* __restrict__ x, unsigned short* __restrict__ xb)
{
    int i = blockIdx.x * 256 + threadIdx.x;   // one float4 -> 4 bf16 per thread
    if (i * 4 < NN * DD) {
        float4 v = *reinterpret_cast<const float4*>(x + (size_t)i * 4);
        ushort4 o;
        o.x = f32_to_bf16_rne(v.x);
        o.y = f32_to_bf16_rne(v.y);
        o.z = f32_to_bf16_rne(v.z);
        o.w = f32_to_bf16_rne(v.w);
        *reinterpret_cast<ushort4*>(xb + (size_t)i * 4) = o;
    }
}

// ---------------------------------------------------------------------------
// Kernel 1: histogram of dst degrees (int atomics into 200 KB, L2-resident)
// ---------------------------------------------------------------------------
__global__ __launch_bounds__(256) void hist_kernel(
    const int* __restrict__ ei, int* __restrict__ counts)
{
    int e = blockIdx.x * 256 + threadIdx.x;
    if (e < NE) atomicAdd(&counts[ei[NE + e]], 1);
}

// ---------------------------------------------------------------------------
// Scan stage 1: per-block sums (49 blocks x 256 thr x int4 = 1024 counts/blk)
// ---------------------------------------------------------------------------
__global__ __launch_bounds__(256) void scan1_kernel(
    const int* __restrict__ counts, int* __restrict__ blocksums)
{
    const int t = threadIdx.x;
    const int base = blockIdx.x * 1024 + t * 4;
    int4 v;
    if (base + 3 < NN) {
        v = *reinterpret_cast<const int4*>(counts + base);
    } else {
        v.x = (base + 0 < NN) ? counts[base + 0] : 0;
        v.y = (base + 1 < NN) ? counts[base + 1] : 0;
        v.z = (base + 2 < NN) ? counts[base + 2] : 0;
        v.w = (base + 3 < NN) ? counts[base + 3] : 0;
    }
    int s = v.x + v.y + v.z + v.w;
    #pragma unroll
    for (int m = 1; m < 64; m <<= 1) s += __shfl_xor(s, m, 64);
    __shared__ int ws[4];
    const int wv = t >> 6, ln = t & 63;
    if (ln == 0) ws[wv] = s;
    __syncthreads();
    if (t == 0) blocksums[blockIdx.x] = ws[0] + ws[1] + ws[2] + ws[3];
}

// ---------------------------------------------------------------------------
// Scan stage 2: one wave scans the 49 block sums -> exclusive block offsets
// ---------------------------------------------------------------------------
__global__ __launch_bounds__(64) void scan2_kernel(
    const int* __restrict__ blocksums, int* __restrict__ blockoffs)
{
    const int ln = threadIdx.x;
    int v = (ln < SCAN_BLKS) ? blocksums[ln] : 0;
    int s = v;
    #pragma unroll
    for (int d = 1; d < 64; d <<= 1) {
        int n = __shfl_up(s, d, 64);
        if (ln >= d) s += n;
    }
    if (ln < SCAN_BLKS) blockoffs[ln] = s - v;   // exclusive
}

// ---------------------------------------------------------------------------
// Scan stage 3: full exclusive scan -> offsets & cursor (int4 stores)
// ---------------------------------------------------------------------------
__global__ __launch_bounds__(256) void scan3_kernel(
    const int* __restrict__ counts, const int* __restrict__ blockoffs,
    int* __restrict__ offsets, int* __restrict__ cursor)
{
    const int t = threadIdx.x;
    const int base = blockIdx.x * 1024 + t * 4;
    int4 v;
    if (base + 3 < NN) {
        v = *reinterpret_cast<const int4*>(counts + base);
    } else {
        v.x = (base + 0 < NN) ? counts[base + 0] : 0;
        v.y = (base + 1 < NN) ? counts[base + 1] : 0;
        v.z = (base + 2 < NN) ? counts[base + 2] : 0;
        v.w = (base + 3 < NN) ? counts[base + 3] : 0;
    }
    const int sum = v.x + v.y + v.z + v.w;
    int s = sum;
    const int wv = t >> 6, ln = t & 63;
    #pragma unroll
    for (int d = 1; d < 64; d <<= 1) {   // inclusive wave scan
        int n = __shfl_up(s, d, 64);
        if (ln >= d) s += n;
    }
    __shared__ int ws[4];
    if (ln == 63) ws[wv] = s;
    __syncthreads();
    int woff = 0;
    #pragma unroll
    for (int i = 0; i < 4; i++) if (i < wv) woff += ws[i];
    const int excl = s - sum + woff + blockoffs[blockIdx.x];
    int4 o;
    o.x = excl;
    o.y = o.x + v.x;
    o.z = o.y + v.y;
    o.w = o.z + v.z;
    if (base + 3 < NN) {
        *reinterpret_cast<int4*>(offsets + base) = o;
        *reinterpret_cast<int4*>(cursor + base) = o;
    } else {
        if (base + 0 < NN) { offsets[base + 0] = o.x; cursor[base + 0] = o.x; }
        if (base + 1 < NN) { offsets[base + 1] = o.y; cursor[base + 1] = o.y; }
        if (base + 2 < NN) { offsets[base + 2] = o.z; cursor[base + 2] = o.z; }
        if (base + 3 < NN) { offsets[base + 3] = o.w; cursor[base + 3] = o.w; }
    }
}

// ---------------------------------------------------------------------------
// Kernel 3: counting-sort edges by dst: srcs_sorted[segment(dst)] = src
// ---------------------------------------------------------------------------
__global__ __launch_bounds__(256) void reorder_kernel(
    const int* __restrict__ ei, int* __restrict__ cursor,
    int* __restrict__ srcs)
{
    int e = blockIdx.x * 256 + threadIdx.x;
    if (e < NE) {
        int src = ei[e];
        int dst = ei[NE + e];
        int p = atomicAdd(&cursor[dst], 1);
        srcs[p] = src;
    }
}

// ---------------------------------------------------------------------------
// Kernel 4 (fused): bf16 gather-mean into LDS (fp32 accum), then exact-fp32
// out = ELU( agg @ W_l^T + b_l + x @ W_r^T ), f32 store.
// Gather: one wave per 8 nodes; per edge one uint32 (2 bf16) per lane =
// 256B/row; 8 edges in flight (MLP depth 8) to cover L2/L3 latency.
// ---------------------------------------------------------------------------
__global__ __launch_bounds__(256) void finish_kernel(
    const int* __restrict__ offsets, const int* __restrict__ counts,
    const int* __restrict__ srcs, const unsigned int* __restrict__ xb,
    const float* __restrict__ x,
    const float* __restrict__ W_l, const float* __restrict__ b_l,
    const float* __restrict__ W_r, float* __restrict__ out)
{
    __shared__ float As[ROWS][260];
    const int row0 = blockIdx.x * ROWS;
    const int t = threadIdx.x;

    // stage x rows (cols 128..255 of the tile), coalesced, exact f32
    for (int i = t; i < ROWS * DD; i += 256) {
        int r = i >> 7, k = i & 127;
        int row = row0 + r;
        As[r][DD + k] = (row < NN) ? x[(size_t)row * DD + k] : 0.f;
    }

    // gather-mean agg rows (cols 0..127); xb row = 64 uint32 (2 bf16 each)
    const int wv = t >> 6;
    const int ln = t & 63;
    for (int rr = 0; rr < 8; rr++) {
        int r = wv * 8 + rr;
        int node = row0 + r;
        float ax = 0.f, ay = 0.f;
        float scale = 0.f;
        if (node < NN) {   // wave-uniform branch
            int beg = __builtin_amdgcn_readfirstlane(offsets[node]);
            int cnt = __builtin_amdgcn_readfirstlane(counts[node]);
            int e = beg, end = beg + cnt;
            for (; e + 8 <= end; e += 8) {
                unsigned int u[8];
                #pragma unroll
                for (int q = 0; q < 8; q++) {
                    int s = srcs[e + q];
                    u[q] = xb[(size_t)s * 64 + ln];
                }
                #pragma unroll
                for (int q = 0; q < 8; q++) {
                    ax += __uint_as_float(u[q] << 16);
                    ay += __uint_as_float(u[q] & 0xFFFF0000u);
                }
            }
            for (; e < end; e++) {
                int s = srcs[e];
                unsigned int u0 = xb[(size_t)s * 64 + ln];
                ax += __uint_as_float(u0 << 16);
                ay += __uint_as_float(u0 & 0xFFFF0000u);
            }
            scale = 1.0f / fmaxf((float)cnt, 1.0f);
        }
        float2 st;
        st.x = ax * scale;
        st.y = ay * scale;
        *reinterpret_cast<float2*>(&As[r][2 * ln]) = st;
    }
    __syncthreads();

    const int rg = t & 7;
    const int cg = t >> 3;
    const int c0 = cg * 4;

    float acc[4][4];
    #pragma unroll
    for (int i = 0; i < 4; i++)
        #pragma unroll
        for (int j = 0; j < 4; j++) acc[i][j] = 0.f;

    // phase 1: agg @ W_l^T
    for (int k = 0; k < DD; k += 4) {
        float4 av[4], wvv[4];
        #pragma unroll
        for (int i = 0; i < 4; i++)
            av[i] = *reinterpret_cast<const float4*>(&As[rg + 8 * i][k]);
        #pragma unroll
        for (int j = 0; j < 4; j++)
            wvv[j] = *reinterpret_cast<const float4*>(W_l + (size_t)(c0 + j) * DD + k);
        #pragma unroll
        for (int i = 0; i < 4; i++)
            #pragma unroll
            for (int j = 0; j < 4; j++)
                acc[i][j] += av[i].x * wvv[j].x + av[i].y * wvv[j].y +
                             av[i].z * wvv[j].z + av[i].w * wvv[j].w;
    }
    // phase 2: x @ W_r^T
    for (int k = 0; k < DD; k += 4) {
        float4 av[4], wvv[4];
        #pragma unroll
        for (int i = 0; i < 4; i++)
            av[i] = *reinterpret_cast<const float4*>(&As[rg + 8 * i][DD + k]);
        #pragma unroll
        for (int j = 0; j < 4; j++)
            wvv[j] = *reinterpret_cast<const float4*>(W_r + (size_t)(c0 + j) * DD + k);
        #pragma unroll
        for (int i = 0; i < 4; i++)
            #pragma unroll
            for (int j = 0; j < 4; j++)
                acc[i][j] += av[i].x * wvv[j].x + av[i].y * wvv[j].y +
                             av[i].z * wvv[j].z + av[i].w * wvv[j].w;
    }

    // epilogue: + b_l, ELU, f32 float4 store
    const float4 bv = *reinterpret_cast<const float4*>(b_l + c0);
    #pragma unroll
    for (int i = 0; i < 4; i++) {
        int row = row0 + rg + 8 * i;
        if (row < NN) {
            float4 o;
            o.x = acc[i][0] + bv.x;
            o.y = acc[i][1] + bv.y;
            o.z = acc[i][2] + bv.z;
            o.w = acc[i][3] + bv.w;
            o.x = o.x > 0.f ? o.x : expm1f(o.x);
            o.y = o.y > 0.f ? o.y : expm1f(o.y);
            o.z = o.z > 0.f ? o.z : expm1f(o.z);
            o.w = o.w > 0.f ? o.w : expm1f(o.w);
            *reinterpret_cast<float4*>(out + (size_t)row * DD + c0) = o;
        }
    }
}

// ---------------------------------------------------------------------------
// Kernel 5: edge_index passthrough as f32 (output 1 of the tuple)
// ---------------------------------------------------------------------------
__global__ __launch_bounds__(256) void eidx_kernel(
    const int* __restrict__ ei, float* __restrict__ oe)
{
    int i = blockIdx.x * 256 + threadIdx.x;
    if (i < 2 * NE) oe[i] = (float)ei[i];
}

extern "C" void kernel_launch(void* const* d_in, const int* in_sizes, int n_in,
                              void* d_out, int out_size, void* d_ws, size_t ws_size,
                              hipStream_t stream)
{
    const float* x   = (const float*)d_in[0];
    const int*   ei  = (const int*)d_in[1];
    const float* W_l = (const float*)d_in[2];
    const float* b_l = (const float*)d_in[3];
    const float* W_r = (const float*)d_in[4];
    float* out = (float*)d_out;

    int* counts    = (int*)d_ws;
    int* offsets   = counts + NN;
    int* cursor    = offsets + NN;
    int* srcs      = cursor + NN;
    int* blocksums = srcs + NE;
    int* blockoffs = blocksums + 64;
    unsigned short* xb = (unsigned short*)(blockoffs + 64);

    // counts must be zero each launch (ws re-poisoned to 0xAA)
    (void)hipMemsetAsync(counts, 0, (size_t)NN * sizeof(int), stream);

    int cb = (NN * DD / 4 + 255) / 256;
    xcvt_kernel<<<cb, 256, 0, stream>>>(x, xb);

    int eb = (NE + 255) / 256;
    hist_kernel<<<eb, 256, 0, stream>>>(ei, counts);
    scan1_kernel<<<SCAN_BLKS, 256, 0, stream>>>(counts, blocksums);
    scan2_kernel<<<1, 64, 0, stream>>>(blocksums, blockoffs);
    scan3_kernel<<<SCAN_BLKS, 256, 0, stream>>>(counts, blockoffs, offsets, cursor);
    reorder_kernel<<<eb, 256, 0, stream>>>(ei, cursor, srcs);

    int fb = (NN + ROWS - 1) / ROWS;
    finish_kernel<<<fb, 256, 0, stream>>>(offsets, counts, srcs,
                                          (const unsigned int*)xb, x,
                                          W_l, b_l, W_r, out);

    int ib = (2 * NE + 255) / 256;
    eidx_kernel<<<ib, 256, 0, stream>>>(ei, out + (size_t)NN * DD);
}